// Round 21
// baseline (253.560 us; speedup 1.0000x reference)
//
#include <hip/hip_runtime.h>
#include <hip/hip_fp16.h>

#define Q_TOT 1024
#define T_TOT 256
#define NPTS  100
#define KD    300
#define EPSV  1e-6f

#define KSTEPS 10            // 10 * 32 = 320 >= 300 (zero-padded K)
#define EXTOFF 40            // front zero-pad for padded rows
#define EXTLEN 672           // f16 units per rotated copy

typedef _Float16 f16;
typedef _Float16 f16x8 __attribute__((ext_vector_type(8)));
typedef float    f32x4 __attribute__((ext_vector_type(4)));
#define MFMA16 __builtin_amdgcn_mfma_f32_16x16x32_f16

// ---------------------------------------------------------------------------
// One sweep: 7 M-tiles x 2 N-tiles (all-fwd or all-bwd; sel/voff compile-
// time).  acc[7][2] = 56 regs.  B is loaded as raw f32 straight from preds
// (L2-resident) and hi/lo-split inline -- bit-identical to the old pfrag
// values (masked zeros at ks=9 == pfrag's zero pad).  A operands phased
// (ah -> ah*bh + ah*bl -> alo -> alo*bh) to stay under the 128-VGPR cliff.
// ---------------------------------------------------------------------------
template<int SEL, int VOFF>
__device__ __forceinline__ void sweep2(const f16 (*sext)[8][EXTLEN],
                                       const float* __restrict__ prow0,
                                       const float* __restrict__ prow1,
                                       int lane, int col, int rg, int cA,
                                       float v2t, const float (&p2v)[2],
                                       float (&minD)[2], int (&minI)[2],
                                       float (*sopen)[256], int ntl0)
{
    f32x4 acc[7][2];
    #pragma unroll
    for (int h = 0; h < 7; ++h)
        #pragma unroll
        for (int nt = 0; nt < 2; ++nt) acc[h][nt] = (f32x4){0.f,0.f,0.f,0.f};

    #pragma clang loop unroll(disable)
    for (int ks = 0; ks < KSTEPS; ++ks) {
        const int k0 = ks*32 + rg*8;
        float x0[8], x1[8];
        if (ks != KSTEPS-1) {                 // uniform branch; aligned 16B loads
            float4 a0 = *(const float4*)(prow0 + k0);
            float4 a1 = *(const float4*)(prow0 + k0 + 4);
            x0[0]=a0.x; x0[1]=a0.y; x0[2]=a0.z; x0[3]=a0.w;
            x0[4]=a1.x; x0[5]=a1.y; x0[6]=a1.z; x0[7]=a1.w;
            float4 b0 = *(const float4*)(prow1 + k0);
            float4 b1 = *(const float4*)(prow1 + k0 + 4);
            x1[0]=b0.x; x1[1]=b0.y; x1[2]=b0.z; x1[3]=b0.w;
            x1[4]=b1.x; x1[5]=b1.y; x1[6]=b1.z; x1[7]=b1.w;
        } else {                              // ks=9: mask k>=300 (no OOB)
            #pragma unroll
            for (int j = 0; j < 8; ++j) {
                x0[j] = (k0+j < KD) ? prow0[k0+j] : 0.f;
                x1[j] = (k0+j < KD) ? prow1[k0+j] : 0.f;
            }
        }
        f16x8 bh[2], bl[2];
        #pragma unroll
        for (int j = 0; j < 8; ++j) {
            f16 h0 = (f16)x0[j]; bh[0][j] = h0; bl[0][j] = (f16)(x0[j] - (float)h0);
            f16 h1 = (f16)x1[j]; bh[1][j] = h1; bl[1][j] = (f16)(x1[j] - (float)h1);
        }
        {
            f16x8 ah[7];
            #pragma unroll
            for (int h = 0; h < 7; ++h) {
                const int idx = EXTOFF + 300 - 48*h - 3*col + 8*rg - cA + 32*ks;
                ah[h] = *(const f16x8*)&sext[SEL][cA][idx];
            }
            #pragma unroll
            for (int nt = 0; nt < 2; ++nt)
                #pragma unroll
                for (int h = 0; h < 7; ++h)
                    acc[h][nt] = MFMA16(ah[h], bh[nt], acc[h][nt], 0,0,0);
            #pragma unroll
            for (int nt = 0; nt < 2; ++nt)
                #pragma unroll
                for (int h = 0; h < 7; ++h)
                    acc[h][nt] = MFMA16(ah[h], bl[nt], acc[h][nt], 0,0,0);
        }
        {
            f16x8 alo[7];
            #pragma unroll
            for (int h = 0; h < 7; ++h) {
                const int idx = EXTOFF + 300 - 48*h - 3*col + 8*rg - cA + 32*ks;
                alo[h] = *(const f16x8*)&sext[SEL+1][cA][idx];
            }
            #pragma unroll
            for (int nt = 0; nt < 2; ++nt)
                #pragma unroll
                for (int h = 0; h < 7; ++h)
                    acc[h][nt] = MFMA16(alo[h], bh[nt], acc[h][nt], 0,0,0);
        }
    }

    #pragma unroll
    for (int h = 0; h < 7; ++h) {
        const int ab = h*16 + rg*4;
        #pragma unroll
        for (int nt = 0; nt < 2; ++nt) {
            const float s2 = v2t + p2v[nt];
            #pragma unroll
            for (int r = 0; r < 4; ++r) {
                const int al = ab + r;
                if (al < 100) {
                    float d2 = fmaxf(fmaf(-2.f, acc[h][nt][r], s2), 0.f) * 0.01f;
                    int vlog = VOFF + al;
                    if (d2 < minD[nt]) { minD[nt] = d2; minI[nt] = vlog; }
                    if (al == 0) sopen[VOFF ? 1 : 0][(ntl0+nt)*16 + col] = d2;
                }
            }
        }
    }
}

// ---------------------------------------------------------------------------
// SINGLE fused kernel: one block = one target t x 256 queries (blockIdx.y
// quarters N).  8 waves x 2 N-tiles; 2 sweeps (fwd, bwd).  No workspace, no
// prep kernel -- B split + p2 + v2 computed in-block (R11-R20's prep+pfrag
// round-trip accounted for most of the ~72 us total-minus-main gap).
// LDS: sext 43K + red 8K + sopen 2K = 53 KB.
// ---------------------------------------------------------------------------
__global__ __launch_bounds__(512) void matcher_fused(
    const float* __restrict__ preds,   // [1024][300]
    const float* __restrict__ tgt,     // [256][300]
    const float* __restrict__ plog,    // [1024][2]
    const float* __restrict__ ptyp,    // [1024][4]
    const float* __restrict__ clog,    // [1024][2]
    const int*   __restrict__ labels,  // [256]
    const int*   __restrict__ iscl,    // [256]
    const float* __restrict__ clw,     // [256]
    float* __restrict__ out)           // [2][1024][256] flat fp32
{
    __shared__ __align__(16) f16 sext[4][8][EXTLEN];  // {Fh,Fl,Rh,Rl} x 8 copies
    __shared__ float redD[1024];
    __shared__ int   redI[1024];
    __shared__ float sopen[2][256];

    const int t    = blockIdx.x;
    const int nb   = blockIdx.y;        // 0..3
    const int tid  = threadIdx.x;
    const int lane = tid & 63;
    const int w    = tid >> 6;
    const int col  = lane & 15;
    const int rg   = lane >> 4;
    const int ntl0 = w*2;               // local N-tile base
    const int ntg0 = nb*16 + ntl0;      // global N-tile base

    // Stage ext (fwd+rev, hi+lo split, 8 byte-rotated copies).
    const float* tg = tgt + t*KD;
    for (int x = tid; x < EXTLEN; x += 512) {
        int e = x - EXTOFF;
        float vF = 0.f, vR = 0.f;
        if (e >= 0 && e < 600) {
            int m = (e >= 300) ? e - 300 : e;
            vF = tg[m];
            int jj = m / 3, c3 = m - 3*jj;
            vR = tg[(NPTS-1-jj)*3 + c3];
        }
        f16 fh = (f16)vF, fl = (f16)(vF - (float)fh);
        f16 rh = (f16)vR, rl = (f16)(vR - (float)rh);
        #pragma unroll
        for (int c = 0; c < 8; ++c) {
            int y = x - c;
            if (y >= 0) {
                sext[0][c][y] = fh; sext[1][c][y] = fl;
                sext[2][c][y] = rh; sext[3][c][y] = rl;
            }
        }
    }

    // v2: per-wave stride-64 + shuffle reduce (same order as before).
    float v2t;
    {
        float s = 0.f;
        for (int k = lane; k < KD; k += 64) s = fmaf(tg[k], tg[k], s);
        #pragma unroll
        for (int m = 1; m < 64; m <<= 1) s += __shfl_xor(s, m, 64);
        v2t = s;
    }

    // p2 for this wave's 32 queries: lane l sums row qbase+(l&31) serially
    // (fp32 reorder vs old prep -- argmin-safe: common-mode per (t,q)).
    float p2v[2];
    {
        const int qbase = ntg0*16;                 // = nb*256 + w*32
        const float4* pr = (const float4*)(preds + (qbase + (lane & 31))*KD);
        float s = 0.f;
        #pragma clang loop unroll(disable)
        for (int i = 0; i < 75; ++i) {
            float4 v = pr[i];
            s = fmaf(v.x,v.x, fmaf(v.y,v.y, fmaf(v.z,v.z, fmaf(v.w,v.w, s))));
        }
        p2v[0] = __shfl(s, col,      64);
        p2v[1] = __shfl(s, 16 + col, 64);
    }

    // B row pointers for this lane's column of the 2 N-tiles.
    const float* prow0 = preds + ((ntg0+0)*16 + col)*KD;
    const float* prow1 = preds + ((ntg0+1)*16 + col)*KD;
    const int cA = (EXTOFF + 300 - 3*col) & 7;     // rotation copy (lane-fixed)
    __syncthreads();

    float minD[2]; int minI[2];
    #pragma unroll
    for (int nt = 0; nt < 2; ++nt) { minD[nt] = 3.4028235e38f; minI[nt] = 0; }

    sweep2<0,  0>(sext, prow0, prow1, lane, col, rg, cA, v2t, p2v, minD, minI, sopen, ntl0);
    sweep2<2,100>(sext, prow0, prow1, lane, col, rg, cA, v2t, p2v, minD, minI, sopen, ntl0);

    #pragma unroll
    for (int nt = 0; nt < 2; ++nt) {
        redD[(ntl0+nt)*64 + lane] = minD[nt];
        redI[(ntl0+nt)*64 + lane] = minI[nt];
    }
    __syncthreads();

    // Epilogue: threads 0..255, one local query each.
    if (tid < 256) {
        const int lq   = tid;
        const int tile = lq >> 4;
        const int cc   = lq & 15;
        const int base = tile*64 + cc;
        float bd = redD[base]; int bi = redI[base];
        #pragma unroll
        for (int g = 1; g < 4; ++g) {
            float d = redD[base + g*16]; int i = redI[base + g*16];
            if (d < bd || (d == bd && i < bi)) { bd = d; bi = i; }
        }
        const int q = nb*256 + lq;
        int mapped = (bi <= NPTS-1) ? bi : (2*NPTS-1 - bi);
        float od   = fminf(sopen[0][lq], sopen[1][lq]);
        int   isc  = iscl[t];
        float geom = isc ? bd : od;
        int   ido  = isc ? mapped : 0;
        geom *= clw[t];

        float t0 = ptyp[q*4+0], t1 = ptyp[q*4+1];
        float t2 = ptyp[q*4+2], t3 = ptyp[q*4+3];
        float mx = fmaxf(fmaxf(t0,t1), fmaxf(t2,t3));
        float e0 = expf(t0-mx), e1 = expf(t1-mx), e2 = expf(t2-mx), e3 = expf(t3-mx);
        float rs = 1.0f/(e0+e1+e2+e3);
        int lab  = labels[t];
        float el = (lab == 0) ? e0 : (lab == 1) ? e1 : (lab == 2) ? e2 : e3;
        float cost = -logf(el*rs + EPSV);
        float v0 = plog[q*2+0], v1 = plog[q*2+1];
        cost += -logf(1.0f/(1.0f + expf(v1-v0)) + EPSV);
        float c0 = clog[q*2+0], c1 = clog[q*2+1];
        float pc = isc ? (1.0f/(1.0f + expf(c0-c1))) : (1.0f/(1.0f + expf(c1-c0)));
        cost += -logf(pc + EPSV);

        float C = geom + cost;
        out[q*T_TOT + t]               = C;
        out[Q_TOT*T_TOT + q*T_TOT + t] = (float)ido;
    }
}

extern "C" void kernel_launch(void* const* d_in, const int* in_sizes, int n_in,
                              void* d_out, int out_size, void* d_ws, size_t ws_size,
                              hipStream_t stream)
{
    const float* preds  = (const float*)d_in[0];  // pred_curve_points (1,1024,100,3)
    const float* plog   = (const float*)d_in[1];  // pred_curve_logits (1,1024,2)
    const float* ptyp   = (const float*)d_in[2];  // pred_curve_type   (1,1024,4)
    const float* clog   = (const float*)d_in[3];  // closed_curve_logits (1,1024,2)
    const float* tgt    = (const float*)d_in[4];  // tgt_curve_points  (256,100,3)
    const int*   labels = (const int*)d_in[5];    // tgt_labels (256)
    const int*   iscl   = (const int*)d_in[6];    // tgt_is_closed (256)
    const float* clw    = (const float*)d_in[7];  // curve_length_weighting (256)
    float* out = (float*)d_out;
    (void)d_ws; (void)ws_size;                    // no workspace needed

    matcher_fused<<<dim3(T_TOT, 4), dim3(512), 0, stream>>>(
        preds, tgt, plog, ptyp, clog, labels, iscl, clw, out);
}